// Round 11
// baseline (525.949 us; speedup 1.0000x reference)
//
#include <hip/hip_runtime.h>
#include <cmath>

#define NS 51
#define ND 50
#define PLANE 1048576            // 1024*1024
#define DOG_ELEMS (ND * PLANE)   // 52428800
#define WPSTRIDE 160             // padded 1-D kernel: 17 zeros | taps | zeros

// ---------------- K0: extract normalized 1-D kernels + radii; zero the zrow -----
__global__ void dog_prep(const float* __restrict__ weight,
                         float* __restrict__ wp,
                         int* __restrict__ rarr,
                         float* __restrict__ zrow, int S) {
    int i = blockIdx.x;
    int t = threadIdx.x;
    int R = (S - 1) >> 1;
    const float* row = weight + ((size_t)i * S + R) * S;   // center row of scale i
    __shared__ float sr[128];
    __shared__ float ssum;
    __shared__ int spad;
    if (t < S) sr[t] = row[t];
    for (int j = t; j < WPSTRIDE; j += blockDim.x) wp[i * WPSTRIDE + j] = 0.f;
    if (i == 0)
        for (int j = t; j < 1024; j += blockDim.x) zrow[j] = 0.f;
    __syncthreads();
    if (t == 0) {
        float sum = 0.f;
        for (int j = 0; j < S; ++j) sum += sr[j];
        int pad = 0;
        while (pad < R && sr[pad] == 0.f) ++pad;
        ssum = sum; spad = pad;
        rarr[i] = R - pad;
    }
    __syncthreads();
    int pad = spad;
    int r = R - pad;
    float inv = 1.f / ssum;
    for (int j = t; j <= 2 * r; j += blockDim.x)
        wp[i * WPSTRIDE + 17 + j] = sr[pad + j] * inv;
}

// ---------------- K1: horizontal blur, scale-chunked (unchanged) ----------------
__global__ __launch_bounds__(256) void dog_hblur(
        const float* __restrict__ in, float* __restrict__ tmpH,
        const float* __restrict__ wp, const int* __restrict__ rarr) {
    const int lo_t[5] = {0, 17, 28, 37, 44};
    const int hi_t[5] = {17, 28, 37, 44, 51};
    int t = threadIdx.x;
    int grp = t >> 7;
    int tl = t & 127;
    int y = (blockIdx.x << 1) | grp;
    int zc = blockIdx.y;
    __shared__ float srow[2][1144];                 // 8 phases x 143
    const float* inrow = in + ((size_t)y << 10);
    for (int e = tl; e < 286; e += 128) {           // 286 float4 = x in [-56,1088)
        int xg = (e << 2) - 56;
        float4 v = make_float4(0.f, 0.f, 0.f, 0.f);
        if (xg >= 0 && xg < 1024) v = *(const float4*)(inrow + xg);
        float vv[4] = {v.x, v.y, v.z, v.w};
        int j = e << 2;
#pragma unroll
        for (int c = 0; c < 4; ++c) {
            int jj = j + c;
            srow[grp][(jj & 7) * 143 + (jj >> 3)] = vv[c];
        }
    }
    __syncthreads();
    const float* s = srow[grp];
    for (int i = lo_t[zc]; i < hi_t[zc]; ++i) {
        int r = rarr[i];
        const float* __restrict__ w = wp + i * WPSTRIDE;
        float acc[8];
#pragma unroll
        for (int k = 0; k < 8; ++k) acc[k] = 0.f;
        int c0 = 56 - r;
        int mcount = ((2 * r + 15) >> 3) << 3;      // >= 2r+8
        for (int m = 0; m < mcount; m += 8) {
            float v[8];
#pragma unroll
            for (int j2 = 0; j2 < 8; ++j2) {
                int q = m + j2 + c0;                // uniform
                v[j2] = s[(q & 7) * 143 + tl + (q >> 3)];
            }
#pragma unroll
            for (int j2 = 0; j2 < 8; ++j2)
#pragma unroll
                for (int k = 0; k < 8; ++k)
                    acc[k] = fmaf(w[17 + m + j2 - k], v[j2], acc[k]);
        }
        float* o = tmpH + (((size_t)i) << 20) + ((size_t)y << 10) + (tl << 3);
        *(float4*)o       = make_float4(acc[0], acc[1], acc[2], acc[3]);
        *(float4*)(o + 4) = make_float4(acc[4], acc[5], acc[6], acc[7]);
    }
}

// ---------------- K2: fused vconv + DoG + 3x3x3 pool + epilogue -----------------
// R10 geometry (256 thr / 4 waves, fp32 tmpH, XCD strip swizzle, nt stores).
// ONE change vs R10: 2-group-lookahead pipeline — 4 named banks, x2-unrolled
// m-loop (step 32, mcount %32==0, zero-padded weights make overrun harmless),
// 16 loads in flight covering ~320 cy before each FMA cluster; cross-scale
// prefetch preloads next scale's g0 AND g1 before the epilogue stores.

#define LOADG(V, MM) do { int gyb_ = gy0 + (MM);                                  \
_Pragma("unroll")                                                                 \
    for (int j_ = 0; j_ < 8; ++j_) {                                              \
        int gy_ = gyb_ + j_;                                                      \
        const float* rp_ = ((unsigned)gy_ < 1024u)                                \
                         ? (plane + ((size_t)gy_ << 10)) : zrow;                  \
        V[j_] = rp_[xi];                                                          \
    } } while (0)

#define FMAG(W, V, MM) do {                                                       \
_Pragma("unroll")                                                                 \
    for (int j_ = 0; j_ < 8; ++j_)                                                \
_Pragma("unroll")                                                                 \
        for (int k_ = 0; k_ < 10; ++k_)                                           \
            acc[k_] = fmaf((W)[17 + (MM) + j_ - k_], V[j_], acc[k_]);             \
    } while (0)

__global__ __launch_bounds__(256, 4) void dog_fused(
        const float* __restrict__ tmpH, float* __restrict__ out,
        const float* __restrict__ wp, const int* __restrict__ rarr,
        const float* __restrict__ sigmas, const float* __restrict__ thr_p,
        const float* __restrict__ zrow) {
    const int jlo_t[5] = {0, 17, 28, 37, 44};
    const int jhi_t[5] = {16, 27, 36, 43, 49};
    // ---- XCD-aware swizzle: p%8 = XCD (dispatch round-robin). combo = strip id.
    int p = blockIdx.x;                   // 0..2815
    int xcd = p & 7;
    int s = p >> 3;                       // 0..351
    int k2 = s >> 5;                      // 0..10
    int ybg = s & 31;                     // 0..31  (same-XCD consecutive y-blocks)
    int combo = (k2 << 3) | xcd;          // 0..87
    if (combo >= 85) return;              // pad blocks
    int wx = combo % 17;                  // 0..16
    int zc = combo / 17;                  // 0..4
    int t = threadIdx.x;
    int lane = t & 63;
    int wv = t >> 6;
    int y0 = ((ybg << 2) | wv) << 3;      // 0..1016, step 8
    int y0u = __builtin_amdgcn_readfirstlane(y0);
    int x = wx * 62 - 1 + lane;           // -1 .. 1054
    int xi = min(max(x, 0), 1023);
    bool xok = ((unsigned)x < 1024u);
    float thr = thr_p[0];
    const float NEG = -__builtin_huge_valf();

    int jlo = jlo_t[zc], jhi = jhi_t[zc];
    int istart = jlo > 0 ? jlo - 1 : 0;
    int iend = (jhi + 2 < 50) ? jhi + 2 : 50;

    float gprev[10], A[8], B[8], Dprev[8], acc[10];
#pragma unroll
    for (int k = 0; k < 10; ++k) { gprev[k] = 0.f; acc[k] = 0.f; }
#pragma unroll
    for (int k = 0; k < 8; ++k) { A[k] = NEG; B[k] = NEG; Dprev[k] = 0.f; }

    // prologue: scale istart params + preload groups 0,1
    const float* plane = tmpH + ((size_t)istart << 20);
    int r0 = rarr[istart];
    int gy0 = y0u - 1 - r0;
    int mcount = ((2 * r0 + 41) >> 5) << 5;          // >= 2r+10, mult of 32
    float vA[8], vB[8], vC[8], vD[8];
    LOADG(vA, 0);
    LOADG(vB, 8);

    for (int i = istart; i <= iend; ++i) {
        const float* __restrict__ w = wp + i * WPSTRIDE;   // this scale's taps
        int mc = mcount;
        int m = 0;
        for (; m + 64 <= mc; m += 32) {
            LOADG(vC, m + 16); LOADG(vD, m + 24);
            FMAG(w, vA, m); FMAG(w, vB, m + 8);
            LOADG(vA, m + 32); LOADG(vB, m + 40);
            FMAG(w, vC, m + 16); FMAG(w, vD, m + 24);
        }
        // tail block: m == mc-32; banks vA=m, vB=m+8 already loaded
        LOADG(vC, m + 16); LOADG(vD, m + 24);
        FMAG(w, vA, m); FMAG(w, vB, m + 8);
        if (i < iend) {                   // prefetch next scale g0,g1 (before stores)
            int rn = rarr[i + 1];
            plane = tmpH + ((size_t)(i + 1) << 20);
            gy0 = y0u - 1 - rn;
            mcount = ((2 * rn + 41) >> 5) << 5;
            LOADG(vA, 0); LOADG(vB, 8);
        }
        FMAG(w, vC, m + 16); FMAG(w, vD, m + 24);
        // ---- epilogue for scale i ----
        if (i > istart) {
            int d = i - 1;
            float sg = sigmas[d];
#pragma unroll
            for (int k = 0; k < 10; ++k) {           // DoG; -inf outside image
                int gy = y0u - 1 + k;
                bool ok = xok && ((unsigned)gy < 1024u);
                gprev[k] = ok ? (gprev[k] - acc[k]) * sg : NEG;
            }
            float ym[8];
#pragma unroll
            for (int k = 0; k < 8; ++k)
                ym[k] = fmaxf(fmaxf(gprev[k], gprev[k + 1]), gprev[k + 2]);
            if (d - 1 >= jlo) {                      // emit j = d-1
                float pooled[8];
#pragma unroll
                for (int k = 0; k < 8; ++k) {
                    float pn = fmaxf(B[k], ym[k]);
                    float l  = __shfl_up(pn, 1);
                    float rr = __shfl_down(pn, 1);
                    pooled[k] = fmaxf(fmaxf(l, rr), pn);
                }
                if (xok && lane >= 1 && lane <= 62) {
                    int j = d - 1;
#pragma unroll
                    for (int k = 0; k < 8; ++k) {
                        float lm = fmaxf(pooled[k] + thr, 0.f);
                        float sm = 1.f - lm + Dprev[k] + thr;
                        float* orow = out + (((size_t)j << 20)
                                     + ((size_t)(y0u + k) << 10));
                        __builtin_nontemporal_store(lm, orow + x);
                        __builtin_nontemporal_store(sm, orow + DOG_ELEMS + x);
                    }
                }
            }
#pragma unroll
            for (int k = 0; k < 8; ++k) {
                B[k] = fmaxf(A[k], ym[k]);
                A[k] = ym[k];
                Dprev[k] = gprev[k + 1];             // dog center rows
            }
        }
#pragma unroll
        for (int k = 0; k < 10; ++k) { gprev[k] = acc[k]; acc[k] = 0.f; }
    }
    if (jhi == 49) {                                 // tail: j=49 (ym_50 = -inf)
        float pooled[8];
#pragma unroll
        for (int k = 0; k < 8; ++k) {
            float pn = B[k];
            float l  = __shfl_up(pn, 1);
            float rr = __shfl_down(pn, 1);
            pooled[k] = fmaxf(fmaxf(l, rr), pn);
        }
        if (xok && lane >= 1 && lane <= 62) {
#pragma unroll
            for (int k = 0; k < 8; ++k) {
                float lm = fmaxf(pooled[k] + thr, 0.f);
                float sm = 1.f - lm + Dprev[k] + thr;
                float* orow = out + (((size_t)49 << 20)
                             + ((size_t)(y0u + k) << 10));
                __builtin_nontemporal_store(lm, orow + x);
                __builtin_nontemporal_store(sm, orow + DOG_ELEMS + x);
            }
        }
    }
}

extern "C" void kernel_launch(void* const* d_in, const int* in_sizes, int n_in,
                              void* d_out, int out_size, void* d_ws, size_t ws_size,
                              hipStream_t stream) {
    const float* input  = (const float*)d_in[0];
    const float* weight = (const float*)d_in[1];
    const float* sigmas = (const float*)d_in[2];
    const float* thr    = (const float*)d_in[3];
    float* out = (float*)d_out;

    int S = 103;
    if (n_in > 1 && in_sizes[1] >= NS) {
        int s2 = in_sizes[1] / NS;
        S = (int)(sqrt((double)s2) + 0.5);
    }

    size_t need = ((size_t)NS * PLANE + NS * WPSTRIDE + 64 + 1024) * 4 + 256;
    if (ws_size < need) return;   // insufficient scratch -> visible validation failure

    float* tmpH = (float*)d_ws;                    // 51 planes (214 MB)
    float* wp   = tmpH + (size_t)NS * WPSTRIDE * 0 + (size_t)NS * PLANE;  // 51*160 floats
    int*   rarr = (int*)(wp + NS * WPSTRIDE);      // 51 ints (64 slots)
    float* zrow = (float*)(rarr + 64);             // 1024 zero floats

    dog_prep <<<NS, 128, 0, stream>>>(weight, wp, rarr, zrow, S);
    dog_hblur<<<dim3(512, 5), 256, 0, stream>>>(input, tmpH, wp, rarr);
    dog_fused<<<2816, 256, 0, stream>>>(tmpH, out, wp, rarr, sigmas, thr, zrow);
}

// Round 12
// 460.692 us; speedup vs baseline: 1.1416x; 1.1416x over previous
//
#include <hip/hip_runtime.h>
#include <cmath>

#define NS 51
#define ND 50
#define PLANE 1048576            // 1024*1024
#define DOG_ELEMS (ND * PLANE)   // 52428800
#define WPSTRIDE 160             // padded 1-D kernel: 17 zeros | taps | zeros

// ---------------- K0: extract normalized 1-D kernels + radii --------------------
__global__ void dog_prep(const float* __restrict__ weight,
                         float* __restrict__ wp,
                         int* __restrict__ rarr, int S) {
    int i = blockIdx.x;
    int t = threadIdx.x;
    int R = (S - 1) >> 1;
    const float* row = weight + ((size_t)i * S + R) * S;   // center row of scale i
    __shared__ float sr[128];
    __shared__ float ssum;
    __shared__ int spad;
    if (t < S) sr[t] = row[t];
    for (int j = t; j < WPSTRIDE; j += blockDim.x) wp[i * WPSTRIDE + j] = 0.f;
    __syncthreads();
    if (t == 0) {
        float sum = 0.f;
        for (int j = 0; j < S; ++j) sum += sr[j];
        int pad = 0;
        while (pad < R && sr[pad] == 0.f) ++pad;
        ssum = sum; spad = pad;
        rarr[i] = R - pad;
    }
    __syncthreads();
    int pad = spad;
    int r = R - pad;
    float inv = 1.f / ssum;
    for (int j = t; j <= 2 * r; j += blockDim.x)
        wp[i * WPSTRIDE + 17 + j] = sr[pad + j] * inv;
}

// ---------------- K1: horizontal blur, scale-chunked (unchanged) ----------------
__global__ __launch_bounds__(256) void dog_hblur(
        const float* __restrict__ in, float* __restrict__ tmpH,
        const float* __restrict__ wp, const int* __restrict__ rarr) {
    const int lo_t[5] = {0, 17, 28, 37, 44};
    const int hi_t[5] = {17, 28, 37, 44, 51};
    int t = threadIdx.x;
    int grp = t >> 7;
    int tl = t & 127;
    int y = (blockIdx.x << 1) | grp;
    int zc = blockIdx.y;
    __shared__ float srow[2][1144];                 // 8 phases x 143
    const float* inrow = in + ((size_t)y << 10);
    for (int e = tl; e < 286; e += 128) {           // 286 float4 = x in [-56,1088)
        int xg = (e << 2) - 56;
        float4 v = make_float4(0.f, 0.f, 0.f, 0.f);
        if (xg >= 0 && xg < 1024) v = *(const float4*)(inrow + xg);
        float vv[4] = {v.x, v.y, v.z, v.w};
        int j = e << 2;
#pragma unroll
        for (int c = 0; c < 4; ++c) {
            int jj = j + c;
            srow[grp][(jj & 7) * 143 + (jj >> 3)] = vv[c];
        }
    }
    __syncthreads();
    const float* s = srow[grp];
    for (int i = lo_t[zc]; i < hi_t[zc]; ++i) {
        int r = rarr[i];
        const float* __restrict__ w = wp + i * WPSTRIDE;
        float acc[8];
#pragma unroll
        for (int k = 0; k < 8; ++k) acc[k] = 0.f;
        int c0 = 56 - r;
        int mcount = ((2 * r + 15) >> 3) << 3;      // >= 2r+8
        for (int m = 0; m < mcount; m += 8) {
            float v[8];
#pragma unroll
            for (int j2 = 0; j2 < 8; ++j2) {
                int q = m + j2 + c0;                // uniform
                v[j2] = s[(q & 7) * 143 + tl + (q >> 3)];
            }
#pragma unroll
            for (int j2 = 0; j2 < 8; ++j2)
#pragma unroll
                for (int k = 0; k < 8; ++k)
                    acc[k] = fmaf(w[17 + m + j2 - k], v[j2], acc[k]);
        }
        float* o = tmpH + (((size_t)i) << 20) + ((size_t)y << 10) + (tl << 3);
        *(float4*)o       = make_float4(acc[0], acc[1], acc[2], acc[3]);
        *(float4*)(o + 4) = make_float4(acc[4], acc[5], acc[6], acc[7]);
    }
}

// ---------------- K2: fused vconv + DoG + 3x3x3 pool + epilogue -----------------
// ONE structural change vs R11: block-level LDS staging. The block's 4 waves
// (y0, y0+8, +16, +24) share one (2r+34)-row x 68-col halo window, staged with
// coalesced float4 loads (9 VMEM instr/thread/scale vs ~66 scalar). Conv reads
// LDS (lanes consecutive -> 2-way, free). 2 barriers/scale; 37 KB LDS keeps
// 4 blocks/CU so cross-block TLP covers stage latency. Epilogue unchanged.

#define FMAG(W, V, MM) do {                                                       \
_Pragma("unroll")                                                                 \
    for (int j_ = 0; j_ < 8; ++j_)                                                \
_Pragma("unroll")                                                                 \
        for (int k_ = 0; k_ < 10; ++k_)                                           \
            acc[k_] = fmaf((W)[17 + (MM) + j_ - k_], V[j_], acc[k_]);             \
    } while (0)

__global__ __launch_bounds__(256, 4) void dog_fused(
        const float* __restrict__ tmpH, float* __restrict__ out,
        const float* __restrict__ wp, const int* __restrict__ rarr,
        const float* __restrict__ sigmas, const float* __restrict__ thr_p) {
    const int jlo_t[5] = {0, 17, 28, 37, 44};
    const int jhi_t[5] = {16, 27, 36, 43, 49};
    // ---- XCD-aware swizzle: p%8 = XCD (dispatch round-robin). combo = strip id.
    int p = blockIdx.x;                   // 0..2815
    int xcd = p & 7;
    int q = p >> 3;                       // 0..351
    int c8 = q >> 5;                      // 0..10
    int ybg = q & 31;                     // 0..31  (same-XCD consecutive y-blocks)
    int combo = (c8 << 3) | xcd;          // 0..87
    if (combo >= 85) return;              // pad blocks
    int wx = combo % 17;                  // 0..16
    int zc = combo / 17;                  // 0..4
    int t = threadIdx.x;
    int lane = t & 63;
    int wv = t >> 6;
    int y0u = __builtin_amdgcn_readfirstlane((ybg << 5) + (wv << 3));
    int x0 = wx * 62 - 1;
    int x = x0 + lane;                    // -1 .. 1054
    int xa = x0 & ~3;                     // 4-aligned stage base col
    int lx = (x0 - xa) + lane;            // lane's col in stage [0..66]
    bool xok = ((unsigned)x < 1024u);
    float thr = thr_p[0];
    const float NEG = -__builtin_huge_valf();

    __shared__ float stage[136 * 68];     // 36.9 KB

    int jlo = jlo_t[zc], jhi = jhi_t[zc];
    int istart = jlo > 0 ? jlo - 1 : 0;
    int iend = (jhi + 2 < 50) ? jhi + 2 : 50;

    float gprev[10], A[8], B[8], Dprev[8];
#pragma unroll
    for (int k = 0; k < 10; ++k) gprev[k] = 0.f;
#pragma unroll
    for (int k = 0; k < 8; ++k) { A[k] = NEG; B[k] = NEG; Dprev[k] = 0.f; }

    for (int i = istart; i <= iend; ++i) {
        int r = rarr[i];
        const float* __restrict__ w = wp + i * WPSTRIDE;
        const float* __restrict__ plane = tmpH + ((size_t)i << 20);
        int mcount = ((2 * r + 17) >> 3) << 3;       // >= 2r+10, mult of 8
        int nrows = mcount + 24;                     // <= 136
        int gy0blk = (ybg << 5) - 1 - r;
        __syncthreads();                             // prev conv reads done
        int nf4 = nrows * 17;
        for (int e = t; e < nf4; e += 256) {
            int row = e / 17, c = e - row * 17;
            int gy = gy0blk + row;
            int gx = xa + (c << 2);
            float4 v = make_float4(0.f, 0.f, 0.f, 0.f);
            if ((unsigned)gy < 1024u) {
                const float* rp = plane + ((size_t)gy << 10);
                if ((unsigned)gx <= 1020u) {
                    v = *(const float4*)(rp + gx);
                } else {
                    float vv[4];
#pragma unroll
                    for (int cc = 0; cc < 4; ++cc) {
                        int g = gx + cc;
                        vv[cc] = ((unsigned)g < 1024u) ? rp[g] : 0.f;
                    }
                    v = make_float4(vv[0], vv[1], vv[2], vv[3]);
                }
            }
            *(float4*)(stage + row * 68 + (c << 2)) = v;
        }
        __syncthreads();                             // stage visible
        float acc[10];
#pragma unroll
        for (int k = 0; k < 10; ++k) acc[k] = 0.f;
        int base = (wv << 3) * 68 + lx;
        for (int m = 0; m < mcount; m += 8) {
            float v[8];
#pragma unroll
            for (int j = 0; j < 8; ++j) v[j] = stage[base + (m + j) * 68];
            FMAG(w, v, m);
        }
        // ---- epilogue for scale i (unchanged) ----
        if (i > istart) {
            int d = i - 1;
            float sg = sigmas[d];
#pragma unroll
            for (int k = 0; k < 10; ++k) {           // DoG; -inf outside image
                int gy = y0u - 1 + k;
                bool ok = xok && ((unsigned)gy < 1024u);
                gprev[k] = ok ? (gprev[k] - acc[k]) * sg : NEG;
            }
            float ym[8];
#pragma unroll
            for (int k = 0; k < 8; ++k)
                ym[k] = fmaxf(fmaxf(gprev[k], gprev[k + 1]), gprev[k + 2]);
            if (d - 1 >= jlo) {                      // emit j = d-1
                float pooled[8];
#pragma unroll
                for (int k = 0; k < 8; ++k) {
                    float pn = fmaxf(B[k], ym[k]);
                    float l  = __shfl_up(pn, 1);
                    float rr = __shfl_down(pn, 1);
                    pooled[k] = fmaxf(fmaxf(l, rr), pn);
                }
                if (xok && lane >= 1 && lane <= 62) {
                    int j = d - 1;
#pragma unroll
                    for (int k = 0; k < 8; ++k) {
                        float lm = fmaxf(pooled[k] + thr, 0.f);
                        float sm = 1.f - lm + Dprev[k] + thr;
                        float* orow = out + (((size_t)j << 20)
                                     + ((size_t)(y0u + k) << 10));
                        __builtin_nontemporal_store(lm, orow + x);
                        __builtin_nontemporal_store(sm, orow + DOG_ELEMS + x);
                    }
                }
            }
#pragma unroll
            for (int k = 0; k < 8; ++k) {
                B[k] = fmaxf(A[k], ym[k]);
                A[k] = ym[k];
                Dprev[k] = gprev[k + 1];             // dog center rows
            }
        }
#pragma unroll
        for (int k = 0; k < 10; ++k) gprev[k] = acc[k];
    }
    if (jhi == 49) {                                 // tail: j=49 (ym_50 = -inf)
        float pooled[8];
#pragma unroll
        for (int k = 0; k < 8; ++k) {
            float pn = B[k];
            float l  = __shfl_up(pn, 1);
            float rr = __shfl_down(pn, 1);
            pooled[k] = fmaxf(fmaxf(l, rr), pn);
        }
        if (xok && lane >= 1 && lane <= 62) {
#pragma unroll
            for (int k = 0; k < 8; ++k) {
                float lm = fmaxf(pooled[k] + thr, 0.f);
                float sm = 1.f - lm + Dprev[k] + thr;
                float* orow = out + (((size_t)49 << 20)
                             + ((size_t)(y0u + k) << 10));
                __builtin_nontemporal_store(lm, orow + x);
                __builtin_nontemporal_store(sm, orow + DOG_ELEMS + x);
            }
        }
    }
}

extern "C" void kernel_launch(void* const* d_in, const int* in_sizes, int n_in,
                              void* d_out, int out_size, void* d_ws, size_t ws_size,
                              hipStream_t stream) {
    const float* input  = (const float*)d_in[0];
    const float* weight = (const float*)d_in[1];
    const float* sigmas = (const float*)d_in[2];
    const float* thr    = (const float*)d_in[3];
    float* out = (float*)d_out;

    int S = 103;
    if (n_in > 1 && in_sizes[1] >= NS) {
        int s2 = in_sizes[1] / NS;
        S = (int)(sqrt((double)s2) + 0.5);
    }

    size_t need = ((size_t)NS * PLANE + NS * WPSTRIDE + 64) * 4 + 256;
    if (ws_size < need) return;   // insufficient scratch -> visible validation failure

    float* tmpH = (float*)d_ws;                    // 51 planes (214 MB)
    float* wp   = tmpH + (size_t)NS * PLANE;       // 51 * 160 floats
    int*   rarr = (int*)(wp + NS * WPSTRIDE);      // 51 ints (64 slots)

    dog_prep <<<NS, 128, 0, stream>>>(weight, wp, rarr, S);
    dog_hblur<<<dim3(512, 5), 256, 0, stream>>>(input, tmpH, wp, rarr);
    dog_fused<<<2816, 256, 0, stream>>>(tmpH, out, wp, rarr, sigmas, thr);
}

// Round 13
// 447.849 us; speedup vs baseline: 1.1744x; 1.0287x over previous
//
#include <hip/hip_runtime.h>
#include <cmath>

#define NS 51
#define ND 50
#define PLANE 1048576            // 1024*1024
#define DOG_ELEMS (ND * PLANE)   // 52428800
#define WPSTRIDE 160             // padded 1-D kernel: 17 zeros | taps | zeros

// ---------------- K0: extract normalized 1-D kernels + radii --------------------
__global__ void dog_prep(const float* __restrict__ weight,
                         float* __restrict__ wp,
                         int* __restrict__ rarr, int S) {
    int i = blockIdx.x;
    int t = threadIdx.x;
    int R = (S - 1) >> 1;
    const float* row = weight + ((size_t)i * S + R) * S;   // center row of scale i
    __shared__ float sr[128];
    __shared__ float ssum;
    __shared__ int spad;
    if (t < S) sr[t] = row[t];
    for (int j = t; j < WPSTRIDE; j += blockDim.x) wp[i * WPSTRIDE + j] = 0.f;
    __syncthreads();
    if (t == 0) {
        float sum = 0.f;
        for (int j = 0; j < S; ++j) sum += sr[j];
        int pad = 0;
        while (pad < R && sr[pad] == 0.f) ++pad;
        ssum = sum; spad = pad;
        rarr[i] = R - pad;
    }
    __syncthreads();
    int pad = spad;
    int r = R - pad;
    float inv = 1.f / ssum;
    for (int j = t; j <= 2 * r; j += blockDim.x)
        wp[i * WPSTRIDE + 17 + j] = sr[pad + j] * inv;
}

// ---------------- K1: horizontal blur, scale-chunked (unchanged) ----------------
__global__ __launch_bounds__(256) void dog_hblur(
        const float* __restrict__ in, float* __restrict__ tmpH,
        const float* __restrict__ wp, const int* __restrict__ rarr) {
    const int lo_t[5] = {0, 17, 28, 37, 44};
    const int hi_t[5] = {17, 28, 37, 44, 51};
    int t = threadIdx.x;
    int grp = t >> 7;
    int tl = t & 127;
    int y = (blockIdx.x << 1) | grp;
    int zc = blockIdx.y;
    __shared__ float srow[2][1144];                 // 8 phases x 143
    const float* inrow = in + ((size_t)y << 10);
    for (int e = tl; e < 286; e += 128) {           // 286 float4 = x in [-56,1088)
        int xg = (e << 2) - 56;
        float4 v = make_float4(0.f, 0.f, 0.f, 0.f);
        if (xg >= 0 && xg < 1024) v = *(const float4*)(inrow + xg);
        float vv[4] = {v.x, v.y, v.z, v.w};
        int j = e << 2;
#pragma unroll
        for (int c = 0; c < 4; ++c) {
            int jj = j + c;
            srow[grp][(jj & 7) * 143 + (jj >> 3)] = vv[c];
        }
    }
    __syncthreads();
    const float* s = srow[grp];
    for (int i = lo_t[zc]; i < hi_t[zc]; ++i) {
        int r = rarr[i];
        const float* __restrict__ w = wp + i * WPSTRIDE;
        float acc[8];
#pragma unroll
        for (int k = 0; k < 8; ++k) acc[k] = 0.f;
        int c0 = 56 - r;
        int mcount = ((2 * r + 15) >> 3) << 3;      // >= 2r+8
        for (int m = 0; m < mcount; m += 8) {
            float v[8];
#pragma unroll
            for (int j2 = 0; j2 < 8; ++j2) {
                int q = m + j2 + c0;                // uniform
                v[j2] = s[(q & 7) * 143 + tl + (q >> 3)];
            }
#pragma unroll
            for (int j2 = 0; j2 < 8; ++j2)
#pragma unroll
                for (int k = 0; k < 8; ++k)
                    acc[k] = fmaf(w[17 + m + j2 - k], v[j2], acc[k]);
        }
        float* o = tmpH + (((size_t)i) << 20) + ((size_t)y << 10) + (tl << 3);
        *(float4*)o       = make_float4(acc[0], acc[1], acc[2], acc[3]);
        *(float4*)(o + 4) = make_float4(acc[4], acc[5], acc[6], acc[7]);
    }
}

// ---------------- K2: fused vconv + DoG + 3x3x3 pool + epilogue -----------------
// ONE change vs R12: 8-wave blocks (512 thr) covering 64 output rows. Halo
// staging amplification (2r+72)/64 ~= 2.2x (was 3.2x); LDS 47.9 KB -> 3
// blocks/CU x 8 waves = 24 waves/CU. Per-thread shape & epilogue unchanged.

#define FMAG(W, V, MM) do {                                                       \
_Pragma("unroll")                                                                 \
    for (int j_ = 0; j_ < 8; ++j_)                                                \
_Pragma("unroll")                                                                 \
        for (int k_ = 0; k_ < 10; ++k_)                                           \
            acc[k_] = fmaf((W)[17 + (MM) + j_ - k_], V[j_], acc[k_]);             \
    } while (0)

__global__ __launch_bounds__(512, 6) void dog_fused(
        const float* __restrict__ tmpH, float* __restrict__ out,
        const float* __restrict__ wp, const int* __restrict__ rarr,
        const float* __restrict__ sigmas, const float* __restrict__ thr_p) {
    const int jlo_t[5] = {0, 17, 28, 37, 44};
    const int jhi_t[5] = {16, 27, 36, 43, 49};
    // ---- XCD-aware swizzle: p%8 = XCD; 16 consecutive y-blocks per strip/XCD.
    int p = blockIdx.x;                   // 0..1407
    int xcd = p & 7;
    int q = p >> 3;                       // 0..175
    int c8 = q >> 4;                      // 0..10
    int ybg = q & 15;                     // 0..15  (same-XCD consecutive y-blocks)
    int combo = (c8 << 3) | xcd;          // 0..87
    if (combo >= 85) return;              // pad blocks
    int wx = combo % 17;                  // 0..16
    int zc = combo / 17;                  // 0..4
    int t = threadIdx.x;
    int lane = t & 63;
    int wv = t >> 6;                      // 0..7
    int y0u = __builtin_amdgcn_readfirstlane((ybg << 6) + (wv << 3));
    int x0 = wx * 62 - 1;
    int x = x0 + lane;                    // -1 .. 1054
    int xa = x0 & ~3;                     // 4-aligned stage base col
    int lx = (x0 - xa) + lane;            // lane's col in stage [0..66]
    bool xok = ((unsigned)x < 1024u);
    float thr = thr_p[0];
    const float NEG = -__builtin_huge_valf();

    __shared__ float stage[176 * 68];     // 47.9 KB

    int jlo = jlo_t[zc], jhi = jhi_t[zc];
    int istart = jlo > 0 ? jlo - 1 : 0;
    int iend = (jhi + 2 < 50) ? jhi + 2 : 50;

    float gprev[10], A[8], B[8], Dprev[8];
#pragma unroll
    for (int k = 0; k < 10; ++k) gprev[k] = 0.f;
#pragma unroll
    for (int k = 0; k < 8; ++k) { A[k] = NEG; B[k] = NEG; Dprev[k] = 0.f; }

    for (int i = istart; i <= iend; ++i) {
        int r = rarr[i];
        const float* __restrict__ w = wp + i * WPSTRIDE;
        const float* __restrict__ plane = tmpH + ((size_t)i << 20);
        int mcount = ((2 * r + 17) >> 3) << 3;       // >= 2r+10, mult of 8
        int nrows = mcount + 64;                     // <= 176
        int gy0blk = (ybg << 6) - 1 - r;
        __syncthreads();                             // prev conv reads done
        int nf4 = nrows * 17;
        for (int e = t; e < nf4; e += 512) {
            int row = e / 17, c = e - row * 17;
            int gy = gy0blk + row;
            int gx = xa + (c << 2);
            float4 v = make_float4(0.f, 0.f, 0.f, 0.f);
            if ((unsigned)gy < 1024u) {
                const float* rp = plane + ((size_t)gy << 10);
                if ((unsigned)gx <= 1020u) {
                    v = *(const float4*)(rp + gx);
                } else {
                    float vv[4];
#pragma unroll
                    for (int cc = 0; cc < 4; ++cc) {
                        int g = gx + cc;
                        vv[cc] = ((unsigned)g < 1024u) ? rp[g] : 0.f;
                    }
                    v = make_float4(vv[0], vv[1], vv[2], vv[3]);
                }
            }
            *(float4*)(stage + row * 68 + (c << 2)) = v;
        }
        __syncthreads();                             // stage visible
        float acc[10];
#pragma unroll
        for (int k = 0; k < 10; ++k) acc[k] = 0.f;
        int base = (wv << 3) * 68 + lx;
        for (int m = 0; m < mcount; m += 8) {
            float v[8];
#pragma unroll
            for (int j = 0; j < 8; ++j) v[j] = stage[base + (m + j) * 68];
            FMAG(w, v, m);
        }
        // ---- epilogue for scale i (unchanged) ----
        if (i > istart) {
            int d = i - 1;
            float sg = sigmas[d];
#pragma unroll
            for (int k = 0; k < 10; ++k) {           // DoG; -inf outside image
                int gy = y0u - 1 + k;
                bool ok = xok && ((unsigned)gy < 1024u);
                gprev[k] = ok ? (gprev[k] - acc[k]) * sg : NEG;
            }
            float ym[8];
#pragma unroll
            for (int k = 0; k < 8; ++k)
                ym[k] = fmaxf(fmaxf(gprev[k], gprev[k + 1]), gprev[k + 2]);
            if (d - 1 >= jlo) {                      // emit j = d-1
                float pooled[8];
#pragma unroll
                for (int k = 0; k < 8; ++k) {
                    float pn = fmaxf(B[k], ym[k]);
                    float l  = __shfl_up(pn, 1);
                    float rr = __shfl_down(pn, 1);
                    pooled[k] = fmaxf(fmaxf(l, rr), pn);
                }
                if (xok && lane >= 1 && lane <= 62) {
                    int j = d - 1;
#pragma unroll
                    for (int k = 0; k < 8; ++k) {
                        float lm = fmaxf(pooled[k] + thr, 0.f);
                        float sm = 1.f - lm + Dprev[k] + thr;
                        float* orow = out + (((size_t)j << 20)
                                     + ((size_t)(y0u + k) << 10));
                        __builtin_nontemporal_store(lm, orow + x);
                        __builtin_nontemporal_store(sm, orow + DOG_ELEMS + x);
                    }
                }
            }
#pragma unroll
            for (int k = 0; k < 8; ++k) {
                B[k] = fmaxf(A[k], ym[k]);
                A[k] = ym[k];
                Dprev[k] = gprev[k + 1];             // dog center rows
            }
        }
#pragma unroll
        for (int k = 0; k < 10; ++k) gprev[k] = acc[k];
    }
    if (jhi == 49) {                                 // tail: j=49 (ym_50 = -inf)
        float pooled[8];
#pragma unroll
        for (int k = 0; k < 8; ++k) {
            float pn = B[k];
            float l  = __shfl_up(pn, 1);
            float rr = __shfl_down(pn, 1);
            pooled[k] = fmaxf(fmaxf(l, rr), pn);
        }
        if (xok && lane >= 1 && lane <= 62) {
#pragma unroll
            for (int k = 0; k < 8; ++k) {
                float lm = fmaxf(pooled[k] + thr, 0.f);
                float sm = 1.f - lm + Dprev[k] + thr;
                float* orow = out + (((size_t)49 << 20)
                             + ((size_t)(y0u + k) << 10));
                __builtin_nontemporal_store(lm, orow + x);
                __builtin_nontemporal_store(sm, orow + DOG_ELEMS + x);
            }
        }
    }
}

extern "C" void kernel_launch(void* const* d_in, const int* in_sizes, int n_in,
                              void* d_out, int out_size, void* d_ws, size_t ws_size,
                              hipStream_t stream) {
    const float* input  = (const float*)d_in[0];
    const float* weight = (const float*)d_in[1];
    const float* sigmas = (const float*)d_in[2];
    const float* thr    = (const float*)d_in[3];
    float* out = (float*)d_out;

    int S = 103;
    if (n_in > 1 && in_sizes[1] >= NS) {
        int s2 = in_sizes[1] / NS;
        S = (int)(sqrt((double)s2) + 0.5);
    }

    size_t need = ((size_t)NS * PLANE + NS * WPSTRIDE + 64) * 4 + 256;
    if (ws_size < need) return;   // insufficient scratch -> visible validation failure

    float* tmpH = (float*)d_ws;                    // 51 planes (214 MB)
    float* wp   = tmpH + (size_t)NS * PLANE;       // 51 * 160 floats
    int*   rarr = (int*)(wp + NS * WPSTRIDE);      // 51 ints (64 slots)

    dog_prep <<<NS, 128, 0, stream>>>(weight, wp, rarr, S);
    dog_hblur<<<dim3(512, 5), 256, 0, stream>>>(input, tmpH, wp, rarr);
    dog_fused<<<1408, 512, 0, stream>>>(tmpH, out, wp, rarr, sigmas, thr);
}

// Round 14
// 379.375 us; speedup vs baseline: 1.3864x; 1.1805x over previous
//
#include <hip/hip_runtime.h>
#include <cmath>

#define NS 51
#define ND 50
#define PLANE 1048576            // 1024*1024
#define DOG_ELEMS (ND * PLANE)   // 52428800
#define WPSTRIDE 160             // padded 1-D kernel: 17 zeros | taps | zeros

// ---------------- K0: extract normalized 1-D kernels + radii --------------------
__global__ void dog_prep(const float* __restrict__ weight,
                         float* __restrict__ wp,
                         int* __restrict__ rarr, int S) {
    int i = blockIdx.x;
    int t = threadIdx.x;
    int R = (S - 1) >> 1;
    const float* row = weight + ((size_t)i * S + R) * S;   // center row of scale i
    __shared__ float sr[128];
    __shared__ float ssum;
    __shared__ int spad;
    if (t < S) sr[t] = row[t];
    for (int j = t; j < WPSTRIDE; j += blockDim.x) wp[i * WPSTRIDE + j] = 0.f;
    __syncthreads();
    if (t == 0) {
        float sum = 0.f;
        for (int j = 0; j < S; ++j) sum += sr[j];
        int pad = 0;
        while (pad < R && sr[pad] == 0.f) ++pad;
        ssum = sum; spad = pad;
        rarr[i] = R - pad;
    }
    __syncthreads();
    int pad = spad;
    int r = R - pad;
    float inv = 1.f / ssum;
    for (int j = t; j <= 2 * r; j += blockDim.x)
        wp[i * WPSTRIDE + 17 + j] = sr[pad + j] * inv;
}

// ---------------- K1: horizontal blur, scale-chunked ----------------------------
// ONE change vs R13: plain LDS layout + ds_read_b128. Thread tl's 8 taps per
// m-step are 8 consecutive elements at c0a + m + 8*tl (c0a = (56-r)&~7, the
// residue d folded into the weight pointer w2 = w+17-d; zero pads absorb the
// shift). Two aligned float4 LDS reads replace 8 scalar b32 (LDS pipe 68->35us).
// float4-index swizzle f' = f + (f>>3) on write AND read spreads banks.
__global__ __launch_bounds__(256) void dog_hblur(
        const float* __restrict__ in, float* __restrict__ tmpH,
        const float* __restrict__ wp, const int* __restrict__ rarr) {
    const int lo_t[5] = {0, 17, 28, 37, 44};
    const int hi_t[5] = {17, 28, 37, 44, 51};
    int t = threadIdx.x;
    int grp = t >> 7;
    int tl = t & 127;
    int y = (blockIdx.x << 1) | grp;
    int zc = blockIdx.y;
    __shared__ float srow[2][1284];                 // 321 swizzled float4 slots
    const float* inrow = in + ((size_t)y << 10);
    for (int f = tl; f < 286; f += 128) {           // elements 4f-56 .. 4f-53
        int xg = (f << 2) - 56;
        float4 v = make_float4(0.f, 0.f, 0.f, 0.f);
        if (xg >= 0 && xg <= 1020) {
            v = *(const float4*)(inrow + xg);
        } else {
            float vv[4];
#pragma unroll
            for (int c = 0; c < 4; ++c) {
                int g = xg + c;
                vv[c] = ((unsigned)g < 1024u) ? inrow[g] : 0.f;
            }
            v = make_float4(vv[0], vv[1], vv[2], vv[3]);
        }
        int fs = f + (f >> 3);                      // swizzled float4 index
        *(float4*)&srow[grp][fs << 2] = v;
    }
    __syncthreads();
    const float* s = srow[grp];
    for (int i = lo_t[zc]; i < hi_t[zc]; ++i) {
        int r = rarr[i];
        int c0 = 56 - r;
        int d = c0 & 7;
        int c0a = c0 - d;
        const float* __restrict__ w2 = wp + i * WPSTRIDE + 17 - d;
        int mcount = ((2 * r + d + 15) >> 3) << 3;  // >= 2r+d+8, mult of 8
        float acc[8];
#pragma unroll
        for (int k = 0; k < 8; ++k) acc[k] = 0.f;
        int ft = (c0a >> 2) + (tl << 1);            // base float4 index
        for (int m = 0; m < mcount; m += 8) {
            int f  = ft + (m >> 2);
            int fa = f + (f >> 3);
            int fb = (f + 1) + ((f + 1) >> 3);
            float4 va = *(const float4*)&s[fa << 2];
            float4 vb = *(const float4*)&s[fb << 2];
            float v[8] = {va.x, va.y, va.z, va.w, vb.x, vb.y, vb.z, vb.w};
#pragma unroll
            for (int j2 = 0; j2 < 8; ++j2)
#pragma unroll
                for (int k = 0; k < 8; ++k)
                    acc[k] = fmaf(w2[m + j2 - k], v[j2], acc[k]);
        }
        float* o = tmpH + (((size_t)i) << 20) + ((size_t)y << 10) + (tl << 3);
        *(float4*)o       = make_float4(acc[0], acc[1], acc[2], acc[3]);
        *(float4*)(o + 4) = make_float4(acc[4], acc[5], acc[6], acc[7]);
    }
}

// ---------------- K2: fused vconv + DoG + 3x3x3 pool + epilogue (unchanged) -----
#define FMAG(W, V, MM) do {                                                       \
_Pragma("unroll")                                                                 \
    for (int j_ = 0; j_ < 8; ++j_)                                                \
_Pragma("unroll")                                                                 \
        for (int k_ = 0; k_ < 10; ++k_)                                           \
            acc[k_] = fmaf((W)[17 + (MM) + j_ - k_], V[j_], acc[k_]);             \
    } while (0)

__global__ __launch_bounds__(512, 6) void dog_fused(
        const float* __restrict__ tmpH, float* __restrict__ out,
        const float* __restrict__ wp, const int* __restrict__ rarr,
        const float* __restrict__ sigmas, const float* __restrict__ thr_p) {
    const int jlo_t[5] = {0, 17, 28, 37, 44};
    const int jhi_t[5] = {16, 27, 36, 43, 49};
    int p = blockIdx.x;                   // 0..1407
    int xcd = p & 7;
    int q = p >> 3;                       // 0..175
    int c8 = q >> 4;                      // 0..10
    int ybg = q & 15;                     // 0..15  (same-XCD consecutive y-blocks)
    int combo = (c8 << 3) | xcd;          // 0..87
    if (combo >= 85) return;              // pad blocks
    int wx = combo % 17;                  // 0..16
    int zc = combo / 17;                  // 0..4
    int t = threadIdx.x;
    int lane = t & 63;
    int wv = t >> 6;                      // 0..7
    int y0u = __builtin_amdgcn_readfirstlane((ybg << 6) + (wv << 3));
    int x0 = wx * 62 - 1;
    int x = x0 + lane;                    // -1 .. 1054
    int xa = x0 & ~3;                     // 4-aligned stage base col
    int lx = (x0 - xa) + lane;            // lane's col in stage [0..66]
    bool xok = ((unsigned)x < 1024u);
    float thr = thr_p[0];
    const float NEG = -__builtin_huge_valf();

    __shared__ float stage[176 * 68];     // 47.9 KB

    int jlo = jlo_t[zc], jhi = jhi_t[zc];
    int istart = jlo > 0 ? jlo - 1 : 0;
    int iend = (jhi + 2 < 50) ? jhi + 2 : 50;

    float gprev[10], A[8], B[8], Dprev[8];
#pragma unroll
    for (int k = 0; k < 10; ++k) gprev[k] = 0.f;
#pragma unroll
    for (int k = 0; k < 8; ++k) { A[k] = NEG; B[k] = NEG; Dprev[k] = 0.f; }

    for (int i = istart; i <= iend; ++i) {
        int r = rarr[i];
        const float* __restrict__ w = wp + i * WPSTRIDE;
        const float* __restrict__ plane = tmpH + ((size_t)i << 20);
        int mcount = ((2 * r + 17) >> 3) << 3;       // >= 2r+10, mult of 8
        int nrows = mcount + 64;                     // <= 176
        int gy0blk = (ybg << 6) - 1 - r;
        __syncthreads();                             // prev conv reads done
        int nf4 = nrows * 17;
        for (int e = t; e < nf4; e += 512) {
            int row = e / 17, c = e - row * 17;
            int gy = gy0blk + row;
            int gx = xa + (c << 2);
            float4 v = make_float4(0.f, 0.f, 0.f, 0.f);
            if ((unsigned)gy < 1024u) {
                const float* rp = plane + ((size_t)gy << 10);
                if ((unsigned)gx <= 1020u) {
                    v = *(const float4*)(rp + gx);
                } else {
                    float vv[4];
#pragma unroll
                    for (int cc = 0; cc < 4; ++cc) {
                        int g = gx + cc;
                        vv[cc] = ((unsigned)g < 1024u) ? rp[g] : 0.f;
                    }
                    v = make_float4(vv[0], vv[1], vv[2], vv[3]);
                }
            }
            *(float4*)(stage + row * 68 + (c << 2)) = v;
        }
        __syncthreads();                             // stage visible
        float acc[10];
#pragma unroll
        for (int k = 0; k < 10; ++k) acc[k] = 0.f;
        int base = (wv << 3) * 68 + lx;
        for (int m = 0; m < mcount; m += 8) {
            float v[8];
#pragma unroll
            for (int j = 0; j < 8; ++j) v[j] = stage[base + (m + j) * 68];
            FMAG(w, v, m);
        }
        // ---- epilogue for scale i ----
        if (i > istart) {
            int d = i - 1;
            float sg = sigmas[d];
#pragma unroll
            for (int k = 0; k < 10; ++k) {           // DoG; -inf outside image
                int gy = y0u - 1 + k;
                bool ok = xok && ((unsigned)gy < 1024u);
                gprev[k] = ok ? (gprev[k] - acc[k]) * sg : NEG;
            }
            float ym[8];
#pragma unroll
            for (int k = 0; k < 8; ++k)
                ym[k] = fmaxf(fmaxf(gprev[k], gprev[k + 1]), gprev[k + 2]);
            if (d - 1 >= jlo) {                      // emit j = d-1
                float pooled[8];
#pragma unroll
                for (int k = 0; k < 8; ++k) {
                    float pn = fmaxf(B[k], ym[k]);
                    float l  = __shfl_up(pn, 1);
                    float rr = __shfl_down(pn, 1);
                    pooled[k] = fmaxf(fmaxf(l, rr), pn);
                }
                if (xok && lane >= 1 && lane <= 62) {
                    int j = d - 1;
#pragma unroll
                    for (int k = 0; k < 8; ++k) {
                        float lm = fmaxf(pooled[k] + thr, 0.f);
                        float sm = 1.f - lm + Dprev[k] + thr;
                        float* orow = out + (((size_t)j << 20)
                                     + ((size_t)(y0u + k) << 10));
                        __builtin_nontemporal_store(lm, orow + x);
                        __builtin_nontemporal_store(sm, orow + DOG_ELEMS + x);
                    }
                }
            }
#pragma unroll
            for (int k = 0; k < 8; ++k) {
                B[k] = fmaxf(A[k], ym[k]);
                A[k] = ym[k];
                Dprev[k] = gprev[k + 1];             // dog center rows
            }
        }
#pragma unroll
        for (int k = 0; k < 10; ++k) gprev[k] = acc[k];
    }
    if (jhi == 49) {                                 // tail: j=49 (ym_50 = -inf)
        float pooled[8];
#pragma unroll
        for (int k = 0; k < 8; ++k) {
            float pn = B[k];
            float l  = __shfl_up(pn, 1);
            float rr = __shfl_down(pn, 1);
            pooled[k] = fmaxf(fmaxf(l, rr), pn);
        }
        if (xok && lane >= 1 && lane <= 62) {
#pragma unroll
            for (int k = 0; k < 8; ++k) {
                float lm = fmaxf(pooled[k] + thr, 0.f);
                float sm = 1.f - lm + Dprev[k] + thr;
                float* orow = out + (((size_t)49 << 20)
                             + ((size_t)(y0u + k) << 10));
                __builtin_nontemporal_store(lm, orow + x);
                __builtin_nontemporal_store(sm, orow + DOG_ELEMS + x);
            }
        }
    }
}

extern "C" void kernel_launch(void* const* d_in, const int* in_sizes, int n_in,
                              void* d_out, int out_size, void* d_ws, size_t ws_size,
                              hipStream_t stream) {
    const float* input  = (const float*)d_in[0];
    const float* weight = (const float*)d_in[1];
    const float* sigmas = (const float*)d_in[2];
    const float* thr    = (const float*)d_in[3];
    float* out = (float*)d_out;

    int S = 103;
    if (n_in > 1 && in_sizes[1] >= NS) {
        int s2 = in_sizes[1] / NS;
        S = (int)(sqrt((double)s2) + 0.5);
    }

    size_t need = ((size_t)NS * PLANE + NS * WPSTRIDE + 64) * 4 + 256;
    if (ws_size < need) return;   // insufficient scratch -> visible validation failure

    float* tmpH = (float*)d_ws;                    // 51 planes (214 MB)
    float* wp   = tmpH + (size_t)NS * PLANE;       // 51 * 160 floats
    int*   rarr = (int*)(wp + NS * WPSTRIDE);      // 51 ints (64 slots)

    dog_prep <<<NS, 128, 0, stream>>>(weight, wp, rarr, S);
    dog_hblur<<<dim3(512, 5), 256, 0, stream>>>(input, tmpH, wp, rarr);
    dog_fused<<<1408, 512, 0, stream>>>(tmpH, out, wp, rarr, sigmas, thr);
}